// Round 16
// baseline (417.928 us; speedup 1.0000x reference)
//
#include <hip/hip_runtime.h>
#include <math.h>
#include <stdint.h>
#include <stddef.h>

typedef __bf16 bf16_t;
typedef __bf16 bf16x8_t __attribute__((ext_vector_type(8)));
typedef float f32x4_t __attribute__((ext_vector_type(4)));

// B=4, L=2048, IN=1024, D=512, DI=1024, DS=128, HD=64, K=4, NH=16, CD=1280,
// DP=2320, NL=2, NC=2. Rows = 8192. SSD chunking: Q=64, 32 chunks, 64 (b,h).
// h: [row][512] bf16 residual stream. zxbc: [row][2304] bf16; dtraw fp32.
// xc_bf: [row][1280] bf16; xcT: [b][ch][t] bf16 (B: 1024..1152, C: 1152..1280).
//
// R8: fused SSD lost 2048-block parallelism; keep the trio.
// R10-R12: 64x128 GEMM tiles for N=512 GEMMs: 454 -> 414 us.
// R13: XCD swizzle neutral-negative -> reverted.  R14: bf16 h (~neutral).
// R15: in_proj on 128x128 @ 512 threads (min staged bytes, 16 waves/CU).

__device__ __forceinline__ float siluf(float v) { return v / (1.f + expf(-v)); }
__device__ __forceinline__ float softplusf(float v) {
  return v > 20.f ? v : log1pf(expf(v));
}

__device__ __forceinline__ void gl_lds16(const bf16_t* g, bf16_t* l) {
  __builtin_amdgcn_global_load_lds(
      (const __attribute__((address_space(1))) void*)g,
      (__attribute__((address_space(3))) void*)l, 16, 0, 0);
}

// ------------- all arrays f32 -> bf16 convert (one launch, 6 slots) --------
__global__ void wcvt_k(const float* __restrict__ s0, bf16_t* __restrict__ d0, int n0,
                       const float* __restrict__ s1, bf16_t* __restrict__ d1, int n1,
                       const float* __restrict__ s2, bf16_t* __restrict__ d2, int n2,
                       const float* __restrict__ s3, bf16_t* __restrict__ d3, int n3,
                       const float* __restrict__ s4, bf16_t* __restrict__ d4, int n4,
                       const float* __restrict__ s5, bf16_t* __restrict__ d5, int n5) {
  const float* s; bf16_t* d; int n;
  switch (blockIdx.y) {
    case 0: s = s0; d = d0; n = n0; break;
    case 1: s = s1; d = d1; n = n1; break;
    case 2: s = s2; d = d2; n = n2; break;
    case 3: s = s3; d = d3; n = n3; break;
    case 4: s = s4; d = d4; n = n4; break;
    default: s = s5; d = d5; n = n5; break;
  }
  int i = (blockIdx.x * 256 + threadIdx.x) * 4;
  if (i >= n) return;
  float4 v = *(const float4*)(s + i);
  __align__(8) bf16_t o[4];
  o[0] = (bf16_t)v.x; o[1] = (bf16_t)v.y; o[2] = (bf16_t)v.z; o[3] = (bf16_t)v.w;
  *(int2*)(d + i) = *(const int2*)o;
}

// ---------------- bf16 MFMA GEMM (64x128 tile, 256 thr) --------------------
// EPI: 1 = bf16 h +bias+GELU; 2 = bf16 h residual RMW.
template <int EPI>
__global__ __launch_bounds__(256) void gemm64_bt(
    const bf16_t* __restrict__ A, const bf16_t* __restrict__ W,
    bf16_t* __restrict__ Ch, const float* __restrict__ bias, int N, int K) {
  __shared__ __align__(16) char smem[49152];
  auto Asb = [&](int b) -> bf16_t* { return (bf16_t*)smem + b * 4096; };
  auto Bsb = [&](int b) -> bf16_t* {
    return (bf16_t*)(smem + 16384) + b * 8192;
  };
  int tid = threadIdx.x;
  int wave = tid >> 6, lane = tid & 63;
  int quad = lane >> 4, l16 = lane & 15;
  int n0 = blockIdx.x * 128;  // n fastest
  int m0 = blockIdx.y * 64;

  f32x4_t acc[8] = {};
  const int NS = K >> 6;

  auto stage = [&](int b, int s) {
    bf16_t* Ad = Asb(b);
    bf16_t* Bd = Bsb(b);
#pragma unroll
    for (int it = 0; it < 2; ++it) {  // A: 64 rows x 8 chunks
      int u = it * 256 + tid;
      int m = u >> 3, pc = u & 7, kc = pc ^ (m & 7);
      gl_lds16(A + (size_t)(m0 + m) * K + s * 64 + kc * 8, Ad + u * 8);
    }
#pragma unroll
    for (int it = 0; it < 4; ++it) {  // B: 128 rows x 8 chunks
      int u = it * 256 + tid;
      int m = u >> 3, pc = u & 7, kc = pc ^ (m & 7);
      gl_lds16(W + (size_t)(n0 + m) * K + s * 64 + kc * 8, Bd + u * 8);
    }
  };

  auto compute = [&](int b) {
    const bf16_t* Ad = Asb(b);
    const bf16_t* Bd = Bsb(b);
#pragma unroll
    for (int half = 0; half < 2; ++half) {
      int cb = half * 4 + quad;
      int Ra = wave * 16 + l16;
      bf16x8_t af = *(const bf16x8_t*)(Ad + (Ra * 8 + (cb ^ (Ra & 7))) * 8);
#pragma unroll
      for (int j = 0; j < 8; ++j) {
        int Rb = j * 16 + l16;
        bf16x8_t bv = *(const bf16x8_t*)(Bd + (Rb * 8 + (cb ^ (Rb & 7))) * 8);
        acc[j] = __builtin_amdgcn_mfma_f32_16x16x32_bf16(af, bv, acc[j], 0, 0, 0);
      }
    }
  };

  stage(0, 0);
  for (int s = 0; s < NS; ++s) {
    if (s + 1 < NS) {
      stage((s + 1) & 1, s + 1);
      __builtin_amdgcn_s_waitcnt(0xF76);  // vmcnt(6): cur tile done
    } else {
      __builtin_amdgcn_s_waitcnt(0xF70);  // vmcnt(0)
    }
    __builtin_amdgcn_s_barrier();
    compute(s & 1);
    __builtin_amdgcn_s_barrier();
  }

  // epilogue: repack 64x128 acc via padded LDS (stride 132, 2-way banks)
  float* eps = (float*)smem;
  __syncthreads();
#pragma unroll
  for (int j = 0; j < 8; ++j)
#pragma unroll
    for (int r = 0; r < 4; ++r)
      eps[(wave * 16 + quad * 4 + r) * 132 + j * 16 + l16] = acc[j][r];
  __syncthreads();
#pragma unroll
  for (int it = 0; it < 8; ++it) {
    int u = it * 256 + tid;
    int rl = u >> 5, cl = (u & 31) * 4;
    float4 v = *(const float4*)(eps + rl * 132 + cl);
    int grow = m0 + rl, gcol = n0 + cl;
    if (EPI == 1) {
      float4 bv = *(const float4*)(bias + gcol);
      v.x += bv.x; v.y += bv.y; v.z += bv.z; v.w += bv.w;
      v.x = 0.5f * v.x * (1.f + erff(v.x * 0.70710678118654752f));
      v.y = 0.5f * v.y * (1.f + erff(v.y * 0.70710678118654752f));
      v.z = 0.5f * v.z * (1.f + erff(v.z * 0.70710678118654752f));
      v.w = 0.5f * v.w * (1.f + erff(v.w * 0.70710678118654752f));
      __align__(8) bf16_t o[4] = {(bf16_t)v.x, (bf16_t)v.y, (bf16_t)v.z,
                                  (bf16_t)v.w};
      *(int2*)(Ch + (size_t)grow * N + gcol) = *(const int2*)o;
    } else {
      bf16_t* cp = Ch + (size_t)grow * N + gcol;
      int2 oi = *(const int2*)cp;
      const bf16_t* op = (const bf16_t*)&oi;
      __align__(8) bf16_t o[4] = {
          (bf16_t)(v.x + (float)op[0]), (bf16_t)(v.y + (float)op[1]),
          (bf16_t)(v.z + (float)op[2]), (bf16_t)(v.w + (float)op[3])};
      *(int2*)cp = *(const int2*)o;
    }
  }
}

// ---------------- bf16 MFMA GEMM (128x128 tile, 512 thr) — in_proj ---------
// 64 KB LDS dbuf -> 2 blocks/CU = 16 waves/CU.  Minimizes staged bytes
// (A x19 + W x64 = 311 MB vs 467 for TM=64).  EPI=3: bf16 zxbc + fp32 dtraw.
__global__ __launch_bounds__(512) void gemm128_bt(
    const bf16_t* __restrict__ A, const bf16_t* __restrict__ W,
    bf16_t* __restrict__ Cb, float* __restrict__ dtraw, int N, int K) {
  __shared__ __align__(16) char smem[65536];
  auto Asb = [&](int b) -> bf16_t* { return (bf16_t*)(smem + b * 16384); };
  auto Bsb = [&](int b) -> bf16_t* {
    return (bf16_t*)(smem + 32768 + b * 16384);
  };
  int tid = threadIdx.x;
  int wave = tid >> 6, lane = tid & 63;
  int quad = lane >> 4, l16 = lane & 15;
  int n0 = blockIdx.x * 128;  // n fastest
  int m0 = blockIdx.y * 128;

  f32x4_t acc[8] = {};  // wave owns rows [wave*16, wave*16+16) x 128 cols
  const int NS = K >> 6;

  auto stage = [&](int b, int s) {
    bf16_t* Ad = Asb(b);
    bf16_t* Bd = Bsb(b);
#pragma unroll
    for (int it = 0; it < 2; ++it) {  // A: 128 rows x 8 chunks = 1024
      int u = it * 512 + tid;
      int m = u >> 3, pc = u & 7, kc = pc ^ (m & 7);
      gl_lds16(A + (size_t)(m0 + m) * K + s * 64 + kc * 8, Ad + u * 8);
    }
#pragma unroll
    for (int it = 0; it < 2; ++it) {  // B: 128 rows x 8 chunks = 1024
      int u = it * 512 + tid;
      int m = u >> 3, pc = u & 7, kc = pc ^ (m & 7);
      gl_lds16(W + (size_t)(n0 + m) * K + s * 64 + kc * 8, Bd + u * 8);
    }
  };

  auto compute = [&](int b) {
    const bf16_t* Ad = Asb(b);
    const bf16_t* Bd = Bsb(b);
#pragma unroll
    for (int half = 0; half < 2; ++half) {
      int cb = half * 4 + quad;
      int Ra = wave * 16 + l16;
      bf16x8_t af = *(const bf16x8_t*)(Ad + (Ra * 8 + (cb ^ (Ra & 7))) * 8);
#pragma unroll
      for (int j = 0; j < 8; ++j) {
        int Rb = j * 16 + l16;
        bf16x8_t bv = *(const bf16x8_t*)(Bd + (Rb * 8 + (cb ^ (Rb & 7))) * 8);
        acc[j] = __builtin_amdgcn_mfma_f32_16x16x32_bf16(af, bv, acc[j], 0, 0, 0);
      }
    }
  };

  stage(0, 0);
  for (int s = 0; s < NS; ++s) {
    if (s + 1 < NS) {
      stage((s + 1) & 1, s + 1);
      __builtin_amdgcn_s_waitcnt(0xF74);  // vmcnt(4): cur tile done
    } else {
      __builtin_amdgcn_s_waitcnt(0xF70);  // vmcnt(0)
    }
    __builtin_amdgcn_s_barrier();
    compute(s & 1);
    __builtin_amdgcn_s_barrier();
  }

  // epilogue: two 64-row halves through padded LDS (64 x 132 fp32 = 33.8 KB)
  float* eps = (float*)smem;
#pragma unroll
  for (int half = 0; half < 2; ++half) {
    __syncthreads();
    if ((wave >> 2) == half) {
      int rloc = (wave & 3) * 16 + quad * 4;
#pragma unroll
      for (int j = 0; j < 8; ++j)
#pragma unroll
        for (int r = 0; r < 4; ++r)
          eps[(rloc + r) * 132 + j * 16 + l16] = acc[j][r];
    }
    __syncthreads();
#pragma unroll
    for (int it = 0; it < 4; ++it) {
      int u = it * 512 + tid;
      int rl = u >> 5, cl = (u & 31) * 4;
      float4 v = *(const float4*)(eps + rl * 132 + cl);
      int grow = m0 + half * 64 + rl, gcol = n0 + cl;
      if (gcol < 2304) {
        __align__(8) bf16_t o[4] = {(bf16_t)v.x, (bf16_t)v.y, (bf16_t)v.z,
                                    (bf16_t)v.w};
        *(int2*)(Cb + (size_t)grow * 2304 + gcol) = *(const int2*)o;
      } else if (gcol < 2320) {
        *(float4*)(dtraw + (size_t)grow * 16 + (gcol - 2304)) = v;
      }
    }
  }
}

// ---------------- LayerNorm D=512, bf16 in -> bf16 out ----------------
__global__ void ln_k(const bf16_t* __restrict__ h, const float* __restrict__ w,
                     const float* __restrict__ b, bf16_t* __restrict__ out) {
  int row = blockIdx.x * 4 + (threadIdx.x >> 6);
  int lane = threadIdx.x & 63;
  bf16x8_t hv = *(const bf16x8_t*)(h + (size_t)row * 512 + lane * 8);
  float vv[8];
  float s = 0.f, sq = 0.f;
#pragma unroll
  for (int j = 0; j < 8; ++j) {
    vv[j] = (float)hv[j];
    s += vv[j];
    sq += vv[j] * vv[j];
  }
#pragma unroll
  for (int off = 32; off >= 1; off >>= 1) {
    s += __shfl_xor(s, off);
    sq += __shfl_xor(sq, off);
  }
  float mean = s * (1.f / 512.f);
  float var = sq * (1.f / 512.f) - mean * mean;
  float rstd = rsqrtf(var + 1e-5f);
  __align__(16) bf16_t ob[8];
#pragma unroll
  for (int j = 0; j < 8; ++j)
    ob[j] = (bf16_t)((vv[j] - mean) * rstd * w[lane * 8 + j] + b[lane * 8 + j]);
  *(int4*)(out + (size_t)row * 512 + lane * 8) = *(const int4*)ob;
}

// ---------------- causal conv (K=4) + SiLU, bf16 in; writes xc_bf + xcT ----
__global__ __launch_bounds__(256) void conv_k(
    const bf16_t* __restrict__ zxbc, const float* __restrict__ cw,
    const float* __restrict__ cb, bf16_t* __restrict__ xc_bf,
    bf16_t* __restrict__ xcT) {
  int blk = blockIdx.x;
  int cc = blk % 20, tc = (blk / 20) % 32, b = blk / 640;
  __shared__ float zin[67][68];
  __shared__ float sconv[64][68];
  __shared__ float4 swv[64];
  __shared__ float scb[64];
  int tid = threadIdx.x;
  int ch0 = cc * 64, t0 = tc * 64;
  if (tid < 64) {
    swv[tid] = *(const float4*)(cw + (ch0 + tid) * 4);
    scb[tid] = cb[ch0 + tid];
  }
  for (int u = tid; u < 536; u += 256) {
    int t = u >> 3, c8 = (u & 7) * 8;
    int tg = t0 + t - 3;
    float4 f0 = make_float4(0.f, 0.f, 0.f, 0.f), f1 = f0;
    if (tg >= 0) {
      bf16x8_t v = *(const bf16x8_t*)(zxbc + (size_t)(b * 2048 + tg) * 2304 +
                                      1024 + ch0 + c8);
      f0 = make_float4(v[0], v[1], v[2], v[3]);
      f1 = make_float4(v[4], v[5], v[6], v[7]);
    }
    *(float4*)&zin[t][c8] = f0;
    *(float4*)&zin[t][c8 + 4] = f1;
  }
  __syncthreads();
  for (int i = tid; i < 64 * 64; i += 256) {
    int t = i >> 6, ch = i & 63;
    float4 w = swv[ch];
    float a = scb[ch] + zin[t][ch] * w.x + zin[t + 1][ch] * w.y +
              zin[t + 2][ch] * w.z + zin[t + 3][ch] * w.w;
    sconv[t][ch] = siluf(a);
  }
  __syncthreads();
  for (int u = tid; u < 512; u += 256) {
    int t = u >> 3, c8 = (u & 7) * 8;
    __align__(16) bf16_t o[8];
#pragma unroll
    for (int j = 0; j < 8; ++j) o[j] = (bf16_t)sconv[t][c8 + j];
    *(bf16x8_t*)(xc_bf + (size_t)(b * 2048 + t0 + t) * 1280 + ch0 + c8) =
        *(const bf16x8_t*)o;
  }
  for (int u = tid; u < 512; u += 256) {
    int ch = u >> 3, t8 = (u & 7) * 8;
    __align__(16) bf16_t o[8];
#pragma unroll
    for (int j = 0; j < 8; ++j) o[j] = (bf16_t)sconv[t8 + j][ch];
    *(bf16x8_t*)(xcT + ((size_t)b * 1280 + ch0 + ch) * 2048 + t0 + t8) =
        *(const bf16x8_t*)o;
  }
}

// ---------------- SSD phase 1: per-chunk state contribution ----------------
__global__ __launch_bounds__(256) void ssd1_k(
    const bf16_t* __restrict__ xcT, const float* __restrict__ dtraw,
    const float* __restrict__ dtbias, const float* __restrict__ Alog,
    bf16_t* __restrict__ Sbuf, float* __restrict__ cumbuf,
    float* __restrict__ Dbuf) {
  int blk = blockIdx.x;
  int c = blk & 31, bh = blk >> 5, h = bh & 15, b = bh >> 4;
  __shared__ __align__(16) bf16_t Xt[64 * 72];   // X^T[p][s] * w2[s]
  __shared__ __align__(16) bf16_t Bt[128 * 72];  // B^T[n][s]
  __shared__ float sw2[64];
  int tid = threadIdx.x;
  size_t row0 = (size_t)b * 2048 + c * 64;
  const bf16_t* xTb = xcT + (size_t)b * 1280 * 2048 + c * 64;

  if (tid < 64) {
    float dt = softplusf(dtraw[(row0 + tid) * 16 + h] + dtbias[h]);
    float v = -expf(Alog[h]) * dt;  // log(dA)
#pragma unroll
    for (int off = 1; off < 64; off <<= 1) {
      float u = __shfl_up(v, off);
      if (tid >= off) v += u;
    }
    cumbuf[(size_t)blk * 64 + tid] = v;
    float c63 = __shfl(v, 63);
    sw2[tid] = expf(c63 - v) * dt;
    if (tid == 63) Dbuf[blk] = expf(v);
  }
#pragma unroll
  for (int i = 0; i < 4; ++i) {  // B^T: 128 rows x 8 chunks
    int u = i * 256 + tid;
    int n = u >> 3, q = u & 7;
    *(bf16x8_t*)(Bt + n * 72 + q * 8) =
        *(const bf16x8_t*)(xTb + (size_t)(1024 + n) * 2048 + q * 8);
  }
  __syncthreads();  // sw2 ready
#pragma unroll
  for (int i = 0; i < 2; ++i) {  // X^T * w2: 64 rows x 8 chunks
    int u = i * 256 + tid;
    int p = u >> 3, q = u & 7;
    bf16x8_t v = *(const bf16x8_t*)(xTb + (size_t)(h * 64 + p) * 2048 + q * 8);
    __align__(16) bf16_t o[8];
#pragma unroll
    for (int j = 0; j < 8; ++j) o[j] = (bf16_t)((float)v[j] * sw2[q * 8 + j]);
    *(bf16x8_t*)(Xt + p * 72 + q * 8) = *(const bf16x8_t*)o;
  }
  __syncthreads();

  int wave = tid >> 6, lane = tid & 63, quad = lane >> 4, l16 = lane & 15;
  f32x4_t acc[8] = {};
#pragma unroll
  for (int kk = 0; kk < 64; kk += 32) {
    bf16x8_t af = *(const bf16x8_t*)(Xt + (wave * 16 + l16) * 72 + kk + quad * 8);
#pragma unroll
    for (int j = 0; j < 8; ++j) {
      bf16x8_t bv = *(const bf16x8_t*)(Bt + (j * 16 + l16) * 72 + kk + quad * 8);
      acc[j] = __builtin_amdgcn_mfma_f32_16x16x32_bf16(af, bv, acc[j], 0, 0, 0);
    }
  }
  bf16_t* Sb = Sbuf + (size_t)blk * 8192;
#pragma unroll
  for (int j = 0; j < 8; ++j) {
    int n = j * 16 + l16;
#pragma unroll
    for (int r = 0; r < 4; ++r) {
      int p = wave * 16 + quad * 4 + r;
      Sb[p * 128 + n] = (bf16_t)acc[j][r];
    }
  }
}

// ---------------- SSD phase 2: inter-chunk state recurrence ----------------
__global__ __launch_bounds__(256) void phB_k(const bf16_t* __restrict__ Sbuf,
                                             const float* __restrict__ Dbuf,
                                             bf16_t* __restrict__ Hbuf) {
  int blk = blockIdx.x;
  int part = blk & 7, bh = blk >> 3;
  int local = threadIdx.x * 4;
  int p = part * 8 + (local >> 7);
  int n = local & 127;
  size_t eoff = (size_t)p * 128 + n;
  float h0 = 0.f, h1 = 0.f, h2 = 0.f, h3 = 0.f;
  for (int c = 0; c < 32; ++c) {
    size_t base = ((size_t)bh * 32 + c) * 8192;
    __align__(8) bf16_t ho[4] = {(bf16_t)h0, (bf16_t)h1, (bf16_t)h2, (bf16_t)h3};
    *(int2*)(Hbuf + base + eoff) = *(const int2*)ho;
    int2 sv = *(const int2*)(Sbuf + base + eoff);
    const bf16_t* sp = (const bf16_t*)&sv;
    float D = Dbuf[bh * 32 + c];
    h0 = h0 * D + (float)sp[0];
    h1 = h1 * D + (float)sp[1];
    h2 = h2 * D + (float)sp[2];
    h3 = h3 * D + (float)sp[3];
  }
}

// ---------------- SSD phase 3: per-chunk output (y bf16) -------------------
__global__ __launch_bounds__(256) void ssd2_k(
    const bf16_t* __restrict__ xc_bf, const bf16_t* __restrict__ xcT,
    const float* __restrict__ dtraw, const float* __restrict__ dtbias,
    const float* __restrict__ cumbuf, const bf16_t* __restrict__ Hbuf,
    bf16_t* __restrict__ y) {
  int blk = blockIdx.x;
  int c = blk & 31, bh = blk >> 5, h = bh & 15, b = bh >> 4;
  __shared__ __align__(16) bf16_t BsHt[64 * 136];  // B[s][n] -> H^T[p][n]
  __shared__ __align__(16) bf16_t Cs[64 * 136];    // C[t][n] -> *exp(cum[t])
  __shared__ __align__(16) bf16_t Xt[64 * 72];     // X^T[p][s]
  __shared__ __align__(16) bf16_t Gs[64 * 72];     // G[t][s]
  __shared__ float scum[64], sdt[64], se[64];
  int tid = threadIdx.x;
  size_t row0 = (size_t)b * 2048 + c * 64;

  if (tid < 64) {
    float cv = cumbuf[(size_t)blk * 64 + tid];
    scum[tid] = cv;
    se[tid] = expf(cv);
    sdt[tid] = softplusf(dtraw[(row0 + tid) * 16 + h] + dtbias[h]);
  }
#pragma unroll
  for (int i = 0; i < 4; ++i) {  // B, C: 64 rows x 16 chunks
    int u = i * 256 + tid;
    int t = u >> 4, q = u & 15;
    const bf16_t* xr = xc_bf + (row0 + t) * 1280 + 1024 + q * 8;
    *(bf16x8_t*)(BsHt + t * 136 + q * 8) = *(const bf16x8_t*)xr;
    *(bf16x8_t*)(Cs + t * 136 + q * 8) = *(const bf16x8_t*)(xr + 128);
  }
#pragma unroll
  for (int i = 0; i < 2; ++i) {  // X^T: 64 rows x 8 chunks
    int u = i * 256 + tid;
    int p = u >> 3, q = u & 7;
    *(bf16x8_t*)(Xt + p * 72 + q * 8) = *(const bf16x8_t*)(
        xcT + ((size_t)b * 1280 + h * 64 + p) * 2048 + c * 64 + q * 8);
  }
  __syncthreads();

  int wave = tid >> 6, lane = tid & 63, quad = lane >> 4, l16 = lane & 15;
  f32x4_t cb[4] = {};
#pragma unroll
  for (int kk = 0; kk < 128; kk += 32) {
    bf16x8_t af = *(const bf16x8_t*)(Cs + (wave * 16 + l16) * 136 + kk + quad * 8);
#pragma unroll
    for (int j = 0; j < 4; ++j) {
      bf16x8_t bv = *(const bf16x8_t*)(BsHt + (j * 16 + l16) * 136 + kk + quad * 8);
      cb[j] = __builtin_amdgcn_mfma_f32_16x16x32_bf16(af, bv, cb[j], 0, 0, 0);
    }
  }
#pragma unroll
  for (int j = 0; j < 4; ++j) {
    int s = j * 16 + l16;
#pragma unroll
    for (int r = 0; r < 4; ++r) {
      int t = wave * 16 + quad * 4 + r;
      float g = 0.f;
      if (s <= t) g = cb[j][r] * expf(scum[t] - scum[s]) * sdt[s];
      Gs[t * 72 + s] = (bf16_t)g;
    }
  }
  __syncthreads();
  {  // scale C by e^cum: 64 rows x 16 chunks, b128 vectorized
#pragma unroll
    for (int i = 0; i < 4; ++i) {
      int u = i * 256 + tid;
      int t = u >> 4, q = u & 15;
      bf16x8_t v = *(const bf16x8_t*)(Cs + t * 136 + q * 8);
      float sc = se[t];
      __align__(16) bf16_t o[8];
#pragma unroll
      for (int j = 0; j < 8; ++j) o[j] = (bf16_t)((float)v[j] * sc);
      *(bf16x8_t*)(Cs + t * 136 + q * 8) = *(const bf16x8_t*)o;
    }
  }
  {  // stage H^T into BsHt: 64 rows x 16 chunks
#pragma unroll
    for (int i = 0; i < 4; ++i) {
      int u = i * 256 + tid;
      int p = u >> 4, q = u & 15;
      *(bf16x8_t*)(BsHt + p * 136 + q * 8) = *(const bf16x8_t*)(
          Hbuf + (size_t)blk * 8192 + p * 128 + q * 8);
    }
  }
  __syncthreads();

  f32x4_t yv[4] = {};
#pragma unroll
  for (int kk = 0; kk < 64; kk += 32) {
    bf16x8_t af = *(const bf16x8_t*)(Gs + (wave * 16 + l16) * 72 + kk + quad * 8);
#pragma unroll
    for (int j = 0; j < 4; ++j) {
      bf16x8_t bv = *(const bf16x8_t*)(Xt + (j * 16 + l16) * 72 + kk + quad * 8);
      yv[j] = __builtin_amdgcn_mfma_f32_16x16x32_bf16(af, bv, yv[j], 0, 0, 0);
    }
  }
#pragma unroll
  for (int kk = 0; kk < 128; kk += 32) {
    bf16x8_t af = *(const bf16x8_t*)(Cs + (wave * 16 + l16) * 136 + kk + quad * 8);
#pragma unroll
    for (int j = 0; j < 4; ++j) {
      bf16x8_t bv = *(const bf16x8_t*)(BsHt + (j * 16 + l16) * 136 + kk + quad * 8);
      yv[j] = __builtin_amdgcn_mfma_f32_16x16x32_bf16(af, bv, yv[j], 0, 0, 0);
    }
  }
#pragma unroll
  for (int j = 0; j < 4; ++j) {
    int p = j * 16 + l16;
#pragma unroll
    for (int r = 0; r < 4; ++r) {
      int t = wave * 16 + quad * 4 + r;
      y[(row0 + t) * 1024 + h * 64 + p] = (bf16_t)yv[j][r];
    }
  }
}

// ---------------- gating + RMSNorm -> bf16 (all-bf16 inputs) ---------------
__global__ void gate_k(const bf16_t* __restrict__ y, const bf16_t* __restrict__ xc_bf,
                       const bf16_t* __restrict__ zxbc, const float* __restrict__ Dp,
                       const float* __restrict__ gw, bf16_t* __restrict__ out) {
  int row = blockIdx.x * 4 + (threadIdx.x >> 6);
  int lane = threadIdx.x & 63;
  const bf16_t* yr = y + (size_t)row * 1024 + lane * 16;
  const bf16_t* xr = xc_bf + (size_t)row * 1280 + lane * 16;
  const bf16_t* zr = zxbc + (size_t)row * 2304 + lane * 16;
  float Dv = Dp[lane >> 2];
  float g[16];
  float ss = 0.f;
#pragma unroll
  for (int q = 0; q < 2; ++q) {
    bf16x8_t yv = *(const bf16x8_t*)(yr + q * 8);
    bf16x8_t xv = *(const bf16x8_t*)(xr + q * 8);
    bf16x8_t zv = *(const bf16x8_t*)(zr + q * 8);
#pragma unroll
    for (int j = 0; j < 8; ++j) {
      float t = ((float)yv[j] + Dv * (float)xv[j]) * siluf((float)zv[j]);
      g[q * 8 + j] = t;
      ss += t * t;
    }
  }
#pragma unroll
  for (int off = 32; off >= 1; off >>= 1) ss += __shfl_xor(ss, off);
  float r = rsqrtf(ss * (1.f / 1024.f) + 1e-5f);
  __align__(16) bf16_t ob[16];
#pragma unroll
  for (int j = 0; j < 16; ++j) ob[j] = (bf16_t)(g[j] * r * gw[lane * 16 + j]);
  bf16_t* op = out + (size_t)row * 1024 + lane * 16;
  *(int4*)op = *(const int4*)ob;
  *(int4*)(op + 8) = *(const int4*)(ob + 8);
}

// ---------------- classifier (bf16 h) ----------------
__global__ void cls_k(const bf16_t* __restrict__ h, const float* __restrict__ w,
                      const float* __restrict__ b, float* __restrict__ out) {
  int row = blockIdx.x * 4 + (threadIdx.x >> 6);
  int lane = threadIdx.x & 63;
  bf16x8_t hv = *(const bf16x8_t*)(h + (size_t)row * 512 + lane * 8);
  float d0 = 0.f, d1 = 0.f;
#pragma unroll
  for (int q = 0; q < 2; ++q) {
    float4 w0 = *(const float4*)(w + lane * 8 + q * 4);
    float4 w1 = *(const float4*)(w + 512 + lane * 8 + q * 4);
    d0 += (float)hv[q * 4 + 0] * w0.x + (float)hv[q * 4 + 1] * w0.y +
          (float)hv[q * 4 + 2] * w0.z + (float)hv[q * 4 + 3] * w0.w;
    d1 += (float)hv[q * 4 + 0] * w1.x + (float)hv[q * 4 + 1] * w1.y +
          (float)hv[q * 4 + 2] * w1.z + (float)hv[q * 4 + 3] * w1.w;
  }
#pragma unroll
  for (int off = 32; off >= 1; off >>= 1) {
    d0 += __shfl_xor(d0, off);
    d1 += __shfl_xor(d1, off);
  }
  if (lane == 0) {
    out[(size_t)row * 2] = d0 + b[0];
    out[(size_t)row * 2 + 1] = d1 + b[1];
  }
}

// ---------------------------------------------------------------------------
extern "C" void kernel_launch(void* const* d_in, const int* in_sizes, int n_in,
                              void* d_out, int out_size, void* d_ws, size_t ws_size,
                              hipStream_t stream) {
  const float* x        = (const float*)d_in[0];
  const float* fc1_w    = (const float*)d_in[1];
  const float* fc1_b    = (const float*)d_in[2];
  const float* ln_w     = (const float*)d_in[3];
  const float* ln_b     = (const float*)d_in[4];
  const float* in_projw = (const float*)d_in[5];
  const float* conv_w   = (const float*)d_in[6];
  const float* conv_b   = (const float*)d_in[7];
  const float* dt_bias  = (const float*)d_in[8];
  const float* A_log    = (const float*)d_in[9];
  const float* D_p      = (const float*)d_in[10];
  const float* gnorm_w  = (const float*)d_in[11];
  const float* out_projw= (const float*)d_in[12];
  const float* cls_w    = (const float*)d_in[13];
  const float* cls_b    = (const float*)d_in[14];
  float* out = (float*)d_out;

  char* p = (char*)d_ws;
  bf16_t* h     = (bf16_t*)p;  p += (size_t)8192 * 512 * 2;      // 8.4 MB
  bf16_t* abf   = (bf16_t*)p;  p += (size_t)8192 * 1024 * 2;     // 16.8 MB
  bf16_t* wfc1  = (bf16_t*)p;  p += (size_t)512 * 1024 * 2;      // 1.0 MB
  bf16_t* win0  = (bf16_t*)p;  p += (size_t)2432 * 512 * 2;      // 2.5 MB (padded)
  bf16_t* win1  = (bf16_t*)p;  p += (size_t)2432 * 512 * 2;      // 2.5 MB (padded)
  bf16_t* wout0 = (bf16_t*)p;  p += (size_t)512 * 1024 * 2;      // 1.0 MB
  bf16_t* wout1 = (bf16_t*)p;  p += (size_t)512 * 1024 * 2;      // 1.0 MB
  bf16_t* zxbc  = (bf16_t*)p;  p += (size_t)8192 * 2304 * 2;     // 37.7 MB
  float*  dtraw = (float*)p;   p += (size_t)8192 * 16 * 4;       // 0.5 MB
  bf16_t* xcbf  = (bf16_t*)p;  p += (size_t)8192 * 1280 * 2;     // 21.0 MB
  bf16_t* xcT   = (bf16_t*)p;  p += (size_t)4 * 1280 * 2048 * 2; // 21.0 MB
  bf16_t* Sbuf  = (bf16_t*)p;  p += (size_t)2048 * 8192 * 2;     // 33.6 MB
  bf16_t* Hbuf  = (bf16_t*)p;  p += (size_t)2048 * 8192 * 2;     // 33.6 MB
  float*  cum   = (float*)p;   p += (size_t)2048 * 64 * 4;       // 0.5 MB
  float*  Dbuf  = (float*)p;   p += (size_t)2048 * 4;
  bf16_t* ybuf  = Sbuf;  // S dead after phB_k; reuse for y (bf16)
  (void)ws_size; (void)in_sizes; (void)n_in; (void)out_size;

  bf16_t* win[2]  = {win0, win1};
  bf16_t* wo[2]   = {wout0, wout1};

  // input + all weights -> bf16, one launch
  wcvt_k<<<dim3(8192, 6), 256, 0, stream>>>(
      x, abf, 8192 * 1024,
      fc1_w, wfc1, 512 * 1024,
      in_projw, win0, 2320 * 512,
      in_projw + (size_t)2320 * 512, win1, 2320 * 512,
      out_projw, wout0, 512 * 1024,
      out_projw + (size_t)512 * 1024, wout1, 512 * 1024);

  // fc1: h = gelu(x @ fc1_w^T + b)
  gemm64_bt<1><<<dim3(4, 128), 256, 0, stream>>>(abf, wfc1, h, fc1_b, 512, 1024);

  for (int l = 0; l < 2; ++l) {
    ln_k<<<2048, 256, 0, stream>>>(h, ln_w + l * 512, ln_b + l * 512, abf);
    gemm128_bt<<<dim3(19, 64), 512, 0, stream>>>(abf, win[l], zxbc, dtraw,
                                                 2320, 512);
    conv_k<<<2560, 256, 0, stream>>>(zxbc, conv_w + (size_t)l * 1280 * 4,
                                     conv_b + (size_t)l * 1280, xcbf, xcT);
    ssd1_k<<<2048, 256, 0, stream>>>(xcT, dtraw, dt_bias + l * 16,
                                     A_log + l * 16, Sbuf, cum, Dbuf);
    phB_k<<<512, 256, 0, stream>>>(Sbuf, Dbuf, Hbuf);
    ssd2_k<<<2048, 256, 0, stream>>>(xcbf, xcT, dtraw, dt_bias + l * 16, cum,
                                     Hbuf, ybuf);
    gate_k<<<2048, 256, 0, stream>>>(ybuf, xcbf, zxbc, D_p + l * 16,
                                     gnorm_w + (size_t)l * 1024, abf);
    gemm64_bt<2><<<dim3(4, 128), 256, 0, stream>>>(abf, wo[l], h, nullptr, 512,
                                                   1024);
  }

  cls_k<<<2048, 256, 0, stream>>>(h, cls_w, cls_b, out);
}

// Round 17
// 410.305 us; speedup vs baseline: 1.0186x; 1.0186x over previous
//
#include <hip/hip_runtime.h>
#include <math.h>
#include <stdint.h>
#include <stddef.h>

typedef __bf16 bf16_t;
typedef __bf16 bf16x8_t __attribute__((ext_vector_type(8)));
typedef float f32x4_t __attribute__((ext_vector_type(4)));

// B=4, L=2048, IN=1024, D=512, DI=1024, DS=128, HD=64, K=4, NH=16, CD=1280,
// DP=2320, NL=2, NC=2. Rows = 8192. SSD chunking: Q=64, 32 chunks, 64 (b,h).
// h: [row][512] bf16 residual stream. zxbc: [row][2304] bf16; dtraw fp32.
// xc_bf: [row][1280] bf16; xcT: [b][ch][t] bf16 (B: 1024..1152, C: 1152..1280).
//
// R8: fused SSD lost 2048-block parallelism; keep the trio.
// R10-R12: 64x128 GEMM tiles (3 blocks/CU): 454 -> 414 us.
// R13 XCD swizzle, R15 128x128@512T: both neutral -> reverted.
// R16: locked at best measured config (R14, 414 us). in_proj ~40 us is
// invariant across 7 tilings -> structural floor for this shape.

__device__ __forceinline__ float siluf(float v) { return v / (1.f + expf(-v)); }
__device__ __forceinline__ float softplusf(float v) {
  return v > 20.f ? v : log1pf(expf(v));
}

__device__ __forceinline__ void gl_lds16(const bf16_t* g, bf16_t* l) {
  __builtin_amdgcn_global_load_lds(
      (const __attribute__((address_space(1))) void*)g,
      (__attribute__((address_space(3))) void*)l, 16, 0, 0);
}

// ------------- all arrays f32 -> bf16 convert (one launch, 6 slots) --------
__global__ void wcvt_k(const float* __restrict__ s0, bf16_t* __restrict__ d0, int n0,
                       const float* __restrict__ s1, bf16_t* __restrict__ d1, int n1,
                       const float* __restrict__ s2, bf16_t* __restrict__ d2, int n2,
                       const float* __restrict__ s3, bf16_t* __restrict__ d3, int n3,
                       const float* __restrict__ s4, bf16_t* __restrict__ d4, int n4,
                       const float* __restrict__ s5, bf16_t* __restrict__ d5, int n5) {
  const float* s; bf16_t* d; int n;
  switch (blockIdx.y) {
    case 0: s = s0; d = d0; n = n0; break;
    case 1: s = s1; d = d1; n = n1; break;
    case 2: s = s2; d = d2; n = n2; break;
    case 3: s = s3; d = d3; n = n3; break;
    case 4: s = s4; d = d4; n = n4; break;
    default: s = s5; d = d5; n = n5; break;
  }
  int i = (blockIdx.x * 256 + threadIdx.x) * 4;
  if (i >= n) return;
  float4 v = *(const float4*)(s + i);
  __align__(8) bf16_t o[4];
  o[0] = (bf16_t)v.x; o[1] = (bf16_t)v.y; o[2] = (bf16_t)v.z; o[3] = (bf16_t)v.w;
  *(int2*)(d + i) = *(const int2*)o;
}

// ---------------- bf16 MFMA GEMM (64x128 tile):  C = A @ W^T ---------------
// 48 KB LDS -> 3 blocks/CU.  Grid: x = n-tile (fastest), y = m-tile (64 rows).
// EPI: 1 = bf16 h +bias+GELU; 2 = bf16 h residual RMW; 3 = bf16 zxbc + dtraw.
template <int EPI>
__global__ __launch_bounds__(256) void gemm64_bt(
    const bf16_t* __restrict__ A, const bf16_t* __restrict__ W,
    bf16_t* __restrict__ Ch, bf16_t* __restrict__ Cb, float* __restrict__ dtraw,
    const float* __restrict__ bias, int N, int K) {
  __shared__ __align__(16) char smem[49152];
  auto Asb = [&](int b) -> bf16_t* { return (bf16_t*)smem + b * 4096; };
  auto Bsb = [&](int b) -> bf16_t* {
    return (bf16_t*)(smem + 16384) + b * 8192;
  };
  int tid = threadIdx.x;
  int wave = tid >> 6, lane = tid & 63;
  int quad = lane >> 4, l16 = lane & 15;
  int n0 = blockIdx.x * 128;  // n fastest
  int m0 = blockIdx.y * 64;

  f32x4_t acc[8] = {};
  const int NS = K >> 6;

  auto stage = [&](int b, int s) {
    bf16_t* Ad = Asb(b);
    bf16_t* Bd = Bsb(b);
#pragma unroll
    for (int it = 0; it < 2; ++it) {  // A: 64 rows x 8 chunks
      int u = it * 256 + tid;
      int m = u >> 3, pc = u & 7, kc = pc ^ (m & 7);
      gl_lds16(A + (size_t)(m0 + m) * K + s * 64 + kc * 8, Ad + u * 8);
    }
#pragma unroll
    for (int it = 0; it < 4; ++it) {  // B: 128 rows x 8 chunks
      int u = it * 256 + tid;
      int m = u >> 3, pc = u & 7, kc = pc ^ (m & 7);
      gl_lds16(W + (size_t)(n0 + m) * K + s * 64 + kc * 8, Bd + u * 8);
    }
  };

  auto compute = [&](int b) {
    const bf16_t* Ad = Asb(b);
    const bf16_t* Bd = Bsb(b);
#pragma unroll
    for (int half = 0; half < 2; ++half) {
      int cb = half * 4 + quad;
      int Ra = wave * 16 + l16;
      bf16x8_t af = *(const bf16x8_t*)(Ad + (Ra * 8 + (cb ^ (Ra & 7))) * 8);
#pragma unroll
      for (int j = 0; j < 8; ++j) {
        int Rb = j * 16 + l16;
        bf16x8_t bv = *(const bf16x8_t*)(Bd + (Rb * 8 + (cb ^ (Rb & 7))) * 8);
        acc[j] = __builtin_amdgcn_mfma_f32_16x16x32_bf16(af, bv, acc[j], 0, 0, 0);
      }
    }
  };

  stage(0, 0);
  for (int s = 0; s < NS; ++s) {
    if (s + 1 < NS) {
      stage((s + 1) & 1, s + 1);
      __builtin_amdgcn_s_waitcnt(0xF76);  // vmcnt(6): cur tile done
    } else {
      __builtin_amdgcn_s_waitcnt(0xF70);  // vmcnt(0)
    }
    __builtin_amdgcn_s_barrier();
    compute(s & 1);
    __builtin_amdgcn_s_barrier();
  }

  // epilogue: repack 64x128 acc via padded LDS (stride 132, 2-way banks)
  float* eps = (float*)smem;
  __syncthreads();
#pragma unroll
  for (int j = 0; j < 8; ++j)
#pragma unroll
    for (int r = 0; r < 4; ++r)
      eps[(wave * 16 + quad * 4 + r) * 132 + j * 16 + l16] = acc[j][r];
  __syncthreads();
#pragma unroll
  for (int it = 0; it < 8; ++it) {
    int u = it * 256 + tid;
    int rl = u >> 5, cl = (u & 31) * 4;
    float4 v = *(const float4*)(eps + rl * 132 + cl);
    int grow = m0 + rl, gcol = n0 + cl;
    if (EPI == 1) {
      float4 bv = *(const float4*)(bias + gcol);
      v.x += bv.x; v.y += bv.y; v.z += bv.z; v.w += bv.w;
      v.x = 0.5f * v.x * (1.f + erff(v.x * 0.70710678118654752f));
      v.y = 0.5f * v.y * (1.f + erff(v.y * 0.70710678118654752f));
      v.z = 0.5f * v.z * (1.f + erff(v.z * 0.70710678118654752f));
      v.w = 0.5f * v.w * (1.f + erff(v.w * 0.70710678118654752f));
      __align__(8) bf16_t o[4] = {(bf16_t)v.x, (bf16_t)v.y, (bf16_t)v.z,
                                  (bf16_t)v.w};
      *(int2*)(Ch + (size_t)grow * N + gcol) = *(const int2*)o;
    } else if (EPI == 2) {
      bf16_t* cp = Ch + (size_t)grow * N + gcol;
      int2 oi = *(const int2*)cp;
      const bf16_t* op = (const bf16_t*)&oi;
      __align__(8) bf16_t o[4] = {
          (bf16_t)(v.x + (float)op[0]), (bf16_t)(v.y + (float)op[1]),
          (bf16_t)(v.z + (float)op[2]), (bf16_t)(v.w + (float)op[3])};
      *(int2*)cp = *(const int2*)o;
    } else {  // EPI == 3
      if (gcol < 2304) {
        __align__(8) bf16_t o[4] = {(bf16_t)v.x, (bf16_t)v.y, (bf16_t)v.z,
                                    (bf16_t)v.w};
        *(int2*)(Cb + (size_t)grow * 2304 + gcol) = *(const int2*)o;
      } else if (gcol < 2320) {
        *(float4*)(dtraw + (size_t)grow * 16 + (gcol - 2304)) = v;
      }
    }
  }
}

// ---------------- LayerNorm D=512, bf16 in -> bf16 out ----------------
__global__ void ln_k(const bf16_t* __restrict__ h, const float* __restrict__ w,
                     const float* __restrict__ b, bf16_t* __restrict__ out) {
  int row = blockIdx.x * 4 + (threadIdx.x >> 6);
  int lane = threadIdx.x & 63;
  bf16x8_t hv = *(const bf16x8_t*)(h + (size_t)row * 512 + lane * 8);
  float vv[8];
  float s = 0.f, sq = 0.f;
#pragma unroll
  for (int j = 0; j < 8; ++j) {
    vv[j] = (float)hv[j];
    s += vv[j];
    sq += vv[j] * vv[j];
  }
#pragma unroll
  for (int off = 32; off >= 1; off >>= 1) {
    s += __shfl_xor(s, off);
    sq += __shfl_xor(sq, off);
  }
  float mean = s * (1.f / 512.f);
  float var = sq * (1.f / 512.f) - mean * mean;
  float rstd = rsqrtf(var + 1e-5f);
  __align__(16) bf16_t ob[8];
#pragma unroll
  for (int j = 0; j < 8; ++j)
    ob[j] = (bf16_t)((vv[j] - mean) * rstd * w[lane * 8 + j] + b[lane * 8 + j]);
  *(int4*)(out + (size_t)row * 512 + lane * 8) = *(const int4*)ob;
}

// ---------------- causal conv (K=4) + SiLU, bf16 in; writes xc_bf + xcT ----
__global__ __launch_bounds__(256) void conv_k(
    const bf16_t* __restrict__ zxbc, const float* __restrict__ cw,
    const float* __restrict__ cb, bf16_t* __restrict__ xc_bf,
    bf16_t* __restrict__ xcT) {
  int blk = blockIdx.x;
  int cc = blk % 20, tc = (blk / 20) % 32, b = blk / 640;
  __shared__ float zin[67][68];
  __shared__ float sconv[64][68];
  __shared__ float4 swv[64];
  __shared__ float scb[64];
  int tid = threadIdx.x;
  int ch0 = cc * 64, t0 = tc * 64;
  if (tid < 64) {
    swv[tid] = *(const float4*)(cw + (ch0 + tid) * 4);
    scb[tid] = cb[ch0 + tid];
  }
  for (int u = tid; u < 536; u += 256) {
    int t = u >> 3, c8 = (u & 7) * 8;
    int tg = t0 + t - 3;
    float4 f0 = make_float4(0.f, 0.f, 0.f, 0.f), f1 = f0;
    if (tg >= 0) {
      bf16x8_t v = *(const bf16x8_t*)(zxbc + (size_t)(b * 2048 + tg) * 2304 +
                                      1024 + ch0 + c8);
      f0 = make_float4(v[0], v[1], v[2], v[3]);
      f1 = make_float4(v[4], v[5], v[6], v[7]);
    }
    *(float4*)&zin[t][c8] = f0;
    *(float4*)&zin[t][c8 + 4] = f1;
  }
  __syncthreads();
  for (int i = tid; i < 64 * 64; i += 256) {
    int t = i >> 6, ch = i & 63;
    float4 w = swv[ch];
    float a = scb[ch] + zin[t][ch] * w.x + zin[t + 1][ch] * w.y +
              zin[t + 2][ch] * w.z + zin[t + 3][ch] * w.w;
    sconv[t][ch] = siluf(a);
  }
  __syncthreads();
  for (int u = tid; u < 512; u += 256) {
    int t = u >> 3, c8 = (u & 7) * 8;
    __align__(16) bf16_t o[8];
#pragma unroll
    for (int j = 0; j < 8; ++j) o[j] = (bf16_t)sconv[t][c8 + j];
    *(bf16x8_t*)(xc_bf + (size_t)(b * 2048 + t0 + t) * 1280 + ch0 + c8) =
        *(const bf16x8_t*)o;
  }
  for (int u = tid; u < 512; u += 256) {
    int ch = u >> 3, t8 = (u & 7) * 8;
    __align__(16) bf16_t o[8];
#pragma unroll
    for (int j = 0; j < 8; ++j) o[j] = (bf16_t)sconv[t8 + j][ch];
    *(bf16x8_t*)(xcT + ((size_t)b * 1280 + ch0 + ch) * 2048 + t0 + t8) =
        *(const bf16x8_t*)o;
  }
}

// ---------------- SSD phase 1: per-chunk state contribution ----------------
__global__ __launch_bounds__(256) void ssd1_k(
    const bf16_t* __restrict__ xcT, const float* __restrict__ dtraw,
    const float* __restrict__ dtbias, const float* __restrict__ Alog,
    bf16_t* __restrict__ Sbuf, float* __restrict__ cumbuf,
    float* __restrict__ Dbuf) {
  int blk = blockIdx.x;
  int c = blk & 31, bh = blk >> 5, h = bh & 15, b = bh >> 4;
  __shared__ __align__(16) bf16_t Xt[64 * 72];   // X^T[p][s] * w2[s]
  __shared__ __align__(16) bf16_t Bt[128 * 72];  // B^T[n][s]
  __shared__ float sw2[64];
  int tid = threadIdx.x;
  size_t row0 = (size_t)b * 2048 + c * 64;
  const bf16_t* xTb = xcT + (size_t)b * 1280 * 2048 + c * 64;

  if (tid < 64) {
    float dt = softplusf(dtraw[(row0 + tid) * 16 + h] + dtbias[h]);
    float v = -expf(Alog[h]) * dt;  // log(dA)
#pragma unroll
    for (int off = 1; off < 64; off <<= 1) {
      float u = __shfl_up(v, off);
      if (tid >= off) v += u;
    }
    cumbuf[(size_t)blk * 64 + tid] = v;
    float c63 = __shfl(v, 63);
    sw2[tid] = expf(c63 - v) * dt;
    if (tid == 63) Dbuf[blk] = expf(v);
  }
#pragma unroll
  for (int i = 0; i < 4; ++i) {  // B^T: 128 rows x 8 chunks
    int u = i * 256 + tid;
    int n = u >> 3, q = u & 7;
    *(bf16x8_t*)(Bt + n * 72 + q * 8) =
        *(const bf16x8_t*)(xTb + (size_t)(1024 + n) * 2048 + q * 8);
  }
  __syncthreads();  // sw2 ready
#pragma unroll
  for (int i = 0; i < 2; ++i) {  // X^T * w2: 64 rows x 8 chunks
    int u = i * 256 + tid;
    int p = u >> 3, q = u & 7;
    bf16x8_t v = *(const bf16x8_t*)(xTb + (size_t)(h * 64 + p) * 2048 + q * 8);
    __align__(16) bf16_t o[8];
#pragma unroll
    for (int j = 0; j < 8; ++j) o[j] = (bf16_t)((float)v[j] * sw2[q * 8 + j]);
    *(bf16x8_t*)(Xt + p * 72 + q * 8) = *(const bf16x8_t*)o;
  }
  __syncthreads();

  int wave = tid >> 6, lane = tid & 63, quad = lane >> 4, l16 = lane & 15;
  f32x4_t acc[8] = {};
#pragma unroll
  for (int kk = 0; kk < 64; kk += 32) {
    bf16x8_t af = *(const bf16x8_t*)(Xt + (wave * 16 + l16) * 72 + kk + quad * 8);
#pragma unroll
    for (int j = 0; j < 8; ++j) {
      bf16x8_t bv = *(const bf16x8_t*)(Bt + (j * 16 + l16) * 72 + kk + quad * 8);
      acc[j] = __builtin_amdgcn_mfma_f32_16x16x32_bf16(af, bv, acc[j], 0, 0, 0);
    }
  }
  bf16_t* Sb = Sbuf + (size_t)blk * 8192;
#pragma unroll
  for (int j = 0; j < 8; ++j) {
    int n = j * 16 + l16;
#pragma unroll
    for (int r = 0; r < 4; ++r) {
      int p = wave * 16 + quad * 4 + r;
      Sb[p * 128 + n] = (bf16_t)acc[j][r];
    }
  }
}

// ---------------- SSD phase 2: inter-chunk state recurrence ----------------
__global__ __launch_bounds__(256) void phB_k(const bf16_t* __restrict__ Sbuf,
                                             const float* __restrict__ Dbuf,
                                             bf16_t* __restrict__ Hbuf) {
  int blk = blockIdx.x;
  int part = blk & 7, bh = blk >> 3;
  int local = threadIdx.x * 4;
  int p = part * 8 + (local >> 7);
  int n = local & 127;
  size_t eoff = (size_t)p * 128 + n;
  float h0 = 0.f, h1 = 0.f, h2 = 0.f, h3 = 0.f;
  for (int c = 0; c < 32; ++c) {
    size_t base = ((size_t)bh * 32 + c) * 8192;
    __align__(8) bf16_t ho[4] = {(bf16_t)h0, (bf16_t)h1, (bf16_t)h2, (bf16_t)h3};
    *(int2*)(Hbuf + base + eoff) = *(const int2*)ho;
    int2 sv = *(const int2*)(Sbuf + base + eoff);
    const bf16_t* sp = (const bf16_t*)&sv;
    float D = Dbuf[bh * 32 + c];
    h0 = h0 * D + (float)sp[0];
    h1 = h1 * D + (float)sp[1];
    h2 = h2 * D + (float)sp[2];
    h3 = h3 * D + (float)sp[3];
  }
}

// ---------------- SSD phase 3: per-chunk output (y bf16) -------------------
__global__ __launch_bounds__(256) void ssd2_k(
    const bf16_t* __restrict__ xc_bf, const bf16_t* __restrict__ xcT,
    const float* __restrict__ dtraw, const float* __restrict__ dtbias,
    const float* __restrict__ cumbuf, const bf16_t* __restrict__ Hbuf,
    bf16_t* __restrict__ y) {
  int blk = blockIdx.x;
  int c = blk & 31, bh = blk >> 5, h = bh & 15, b = bh >> 4;
  __shared__ __align__(16) bf16_t BsHt[64 * 136];  // B[s][n] -> H^T[p][n]
  __shared__ __align__(16) bf16_t Cs[64 * 136];    // C[t][n] -> *exp(cum[t])
  __shared__ __align__(16) bf16_t Xt[64 * 72];     // X^T[p][s]
  __shared__ __align__(16) bf16_t Gs[64 * 72];     // G[t][s]
  __shared__ float scum[64], sdt[64], se[64];
  int tid = threadIdx.x;
  size_t row0 = (size_t)b * 2048 + c * 64;

  if (tid < 64) {
    float cv = cumbuf[(size_t)blk * 64 + tid];
    scum[tid] = cv;
    se[tid] = expf(cv);
    sdt[tid] = softplusf(dtraw[(row0 + tid) * 16 + h] + dtbias[h]);
  }
#pragma unroll
  for (int i = 0; i < 4; ++i) {  // B, C: 64 rows x 16 chunks
    int u = i * 256 + tid;
    int t = u >> 4, q = u & 15;
    const bf16_t* xr = xc_bf + (row0 + t) * 1280 + 1024 + q * 8;
    *(bf16x8_t*)(BsHt + t * 136 + q * 8) = *(const bf16x8_t*)xr;
    *(bf16x8_t*)(Cs + t * 136 + q * 8) = *(const bf16x8_t*)(xr + 128);
  }
#pragma unroll
  for (int i = 0; i < 2; ++i) {  // X^T: 64 rows x 8 chunks
    int u = i * 256 + tid;
    int p = u >> 3, q = u & 7;
    *(bf16x8_t*)(Xt + p * 72 + q * 8) = *(const bf16x8_t*)(
        xcT + ((size_t)b * 1280 + h * 64 + p) * 2048 + c * 64 + q * 8);
  }
  __syncthreads();

  int wave = tid >> 6, lane = tid & 63, quad = lane >> 4, l16 = lane & 15;
  f32x4_t cb[4] = {};
#pragma unroll
  for (int kk = 0; kk < 128; kk += 32) {
    bf16x8_t af = *(const bf16x8_t*)(Cs + (wave * 16 + l16) * 136 + kk + quad * 8);
#pragma unroll
    for (int j = 0; j < 4; ++j) {
      bf16x8_t bv = *(const bf16x8_t*)(BsHt + (j * 16 + l16) * 136 + kk + quad * 8);
      cb[j] = __builtin_amdgcn_mfma_f32_16x16x32_bf16(af, bv, cb[j], 0, 0, 0);
    }
  }
#pragma unroll
  for (int j = 0; j < 4; ++j) {
    int s = j * 16 + l16;
#pragma unroll
    for (int r = 0; r < 4; ++r) {
      int t = wave * 16 + quad * 4 + r;
      float g = 0.f;
      if (s <= t) g = cb[j][r] * expf(scum[t] - scum[s]) * sdt[s];
      Gs[t * 72 + s] = (bf16_t)g;
    }
  }
  __syncthreads();
  {  // scale C by e^cum: 64 rows x 16 chunks, b128 vectorized
#pragma unroll
    for (int i = 0; i < 4; ++i) {
      int u = i * 256 + tid;
      int t = u >> 4, q = u & 15;
      bf16x8_t v = *(const bf16x8_t*)(Cs + t * 136 + q * 8);
      float sc = se[t];
      __align__(16) bf16_t o[8];
#pragma unroll
      for (int j = 0; j < 8; ++j) o[j] = (bf16_t)((float)v[j] * sc);
      *(bf16x8_t*)(Cs + t * 136 + q * 8) = *(const bf16x8_t*)o;
    }
  }
  {  // stage H^T into BsHt: 64 rows x 16 chunks
#pragma unroll
    for (int i = 0; i < 4; ++i) {
      int u = i * 256 + tid;
      int p = u >> 4, q = u & 15;
      *(bf16x8_t*)(BsHt + p * 136 + q * 8) = *(const bf16x8_t*)(
          Hbuf + (size_t)blk * 8192 + p * 128 + q * 8);
    }
  }
  __syncthreads();

  f32x4_t yv[4] = {};
#pragma unroll
  for (int kk = 0; kk < 64; kk += 32) {
    bf16x8_t af = *(const bf16x8_t*)(Gs + (wave * 16 + l16) * 72 + kk + quad * 8);
#pragma unroll
    for (int j = 0; j < 4; ++j) {
      bf16x8_t bv = *(const bf16x8_t*)(Xt + (j * 16 + l16) * 72 + kk + quad * 8);
      yv[j] = __builtin_amdgcn_mfma_f32_16x16x32_bf16(af, bv, yv[j], 0, 0, 0);
    }
  }
#pragma unroll
  for (int kk = 0; kk < 128; kk += 32) {
    bf16x8_t af = *(const bf16x8_t*)(Cs + (wave * 16 + l16) * 136 + kk + quad * 8);
#pragma unroll
    for (int j = 0; j < 4; ++j) {
      bf16x8_t bv = *(const bf16x8_t*)(BsHt + (j * 16 + l16) * 136 + kk + quad * 8);
      yv[j] = __builtin_amdgcn_mfma_f32_16x16x32_bf16(af, bv, yv[j], 0, 0, 0);
    }
  }
#pragma unroll
  for (int j = 0; j < 4; ++j) {
    int p = j * 16 + l16;
#pragma unroll
    for (int r = 0; r < 4; ++r) {
      int t = wave * 16 + quad * 4 + r;
      y[(row0 + t) * 1024 + h * 64 + p] = (bf16_t)yv[j][r];
    }
  }
}

// ---------------- gating + RMSNorm -> bf16 (all-bf16 inputs) ---------------
__global__ void gate_k(const bf16_t* __restrict__ y, const bf16_t* __restrict__ xc_bf,
                       const bf16_t* __restrict__ zxbc, const float* __restrict__ Dp,
                       const float* __restrict__ gw, bf16_t* __restrict__ out) {
  int row = blockIdx.x * 4 + (threadIdx.x >> 6);
  int lane = threadIdx.x & 63;
  const bf16_t* yr = y + (size_t)row * 1024 + lane * 16;
  const bf16_t* xr = xc_bf + (size_t)row * 1280 + lane * 16;
  const bf16_t* zr = zxbc + (size_t)row * 2304 + lane * 16;
  float Dv = Dp[lane >> 2];
  float g[16];
  float ss = 0.f;
#pragma unroll
  for (int q = 0; q < 2; ++q) {
    bf16x8_t yv = *(const bf16x8_t*)(yr + q * 8);
    bf16x8_t xv = *(const bf16x8_t*)(xr + q * 8);
    bf16x8_t zv = *(const bf16x8_t*)(zr + q * 8);
#pragma unroll
    for (int j = 0; j < 8; ++j) {
      float t = ((float)yv[j] + Dv * (float)xv[j]) * siluf((float)zv[j]);
      g[q * 8 + j] = t;
      ss += t * t;
    }
  }
#pragma unroll
  for (int off = 32; off >= 1; off >>= 1) ss += __shfl_xor(ss, off);
  float r = rsqrtf(ss * (1.f / 1024.f) + 1e-5f);
  __align__(16) bf16_t ob[16];
#pragma unroll
  for (int j = 0; j < 16; ++j) ob[j] = (bf16_t)(g[j] * r * gw[lane * 16 + j]);
  bf16_t* op = out + (size_t)row * 1024 + lane * 16;
  *(int4*)op = *(const int4*)ob;
  *(int4*)(op + 8) = *(const int4*)(ob + 8);
}

// ---------------- classifier (bf16 h) ----------------
__global__ void cls_k(const bf16_t* __restrict__ h, const float* __restrict__ w,
                      const float* __restrict__ b, float* __restrict__ out) {
  int row = blockIdx.x * 4 + (threadIdx.x >> 6);
  int lane = threadIdx.x & 63;
  bf16x8_t hv = *(const bf16x8_t*)(h + (size_t)row * 512 + lane * 8);
  float d0 = 0.f, d1 = 0.f;
#pragma unroll
  for (int q = 0; q < 2; ++q) {
    float4 w0 = *(const float4*)(w + lane * 8 + q * 4);
    float4 w1 = *(const float4*)(w + 512 + lane * 8 + q * 4);
    d0 += (float)hv[q * 4 + 0] * w0.x + (float)hv[q * 4 + 1] * w0.y +
          (float)hv[q * 4 + 2] * w0.z + (float)hv[q * 4 + 3] * w0.w;
    d1 += (float)hv[q * 4 + 0] * w1.x + (float)hv[q * 4 + 1] * w1.y +
          (float)hv[q * 4 + 2] * w1.z + (float)hv[q * 4 + 3] * w1.w;
  }
#pragma unroll
  for (int off = 32; off >= 1; off >>= 1) {
    d0 += __shfl_xor(d0, off);
    d1 += __shfl_xor(d1, off);
  }
  if (lane == 0) {
    out[(size_t)row * 2] = d0 + b[0];
    out[(size_t)row * 2 + 1] = d1 + b[1];
  }
}

// ---------------------------------------------------------------------------
extern "C" void kernel_launch(void* const* d_in, const int* in_sizes, int n_in,
                              void* d_out, int out_size, void* d_ws, size_t ws_size,
                              hipStream_t stream) {
  const float* x        = (const float*)d_in[0];
  const float* fc1_w    = (const float*)d_in[1];
  const float* fc1_b    = (const float*)d_in[2];
  const float* ln_w     = (const float*)d_in[3];
  const float* ln_b     = (const float*)d_in[4];
  const float* in_projw = (const float*)d_in[5];
  const float* conv_w   = (const float*)d_in[6];
  const float* conv_b   = (const float*)d_in[7];
  const float* dt_bias  = (const float*)d_in[8];
  const float* A_log    = (const float*)d_in[9];
  const float* D_p      = (const float*)d_in[10];
  const float* gnorm_w  = (const float*)d_in[11];
  const float* out_projw= (const float*)d_in[12];
  const float* cls_w    = (const float*)d_in[13];
  const float* cls_b    = (const float*)d_in[14];
  float* out = (float*)d_out;

  char* p = (char*)d_ws;
  bf16_t* h     = (bf16_t*)p;  p += (size_t)8192 * 512 * 2;      // 8.4 MB
  bf16_t* abf   = (bf16_t*)p;  p += (size_t)8192 * 1024 * 2;     // 16.8 MB
  bf16_t* wfc1  = (bf16_t*)p;  p += (size_t)512 * 1024 * 2;      // 1.0 MB
  bf16_t* win0  = (bf16_t*)p;  p += (size_t)2432 * 512 * 2;      // 2.5 MB (padded)
  bf16_t* win1  = (bf16_t*)p;  p += (size_t)2432 * 512 * 2;      // 2.5 MB (padded)
  bf16_t* wout0 = (bf16_t*)p;  p += (size_t)512 * 1024 * 2;      // 1.0 MB
  bf16_t* wout1 = (bf16_t*)p;  p += (size_t)512 * 1024 * 2;      // 1.0 MB
  bf16_t* zxbc  = (bf16_t*)p;  p += (size_t)8192 * 2304 * 2;     // 37.7 MB
  float*  dtraw = (float*)p;   p += (size_t)8192 * 16 * 4;       // 0.5 MB
  bf16_t* xcbf  = (bf16_t*)p;  p += (size_t)8192 * 1280 * 2;     // 21.0 MB
  bf16_t* xcT   = (bf16_t*)p;  p += (size_t)4 * 1280 * 2048 * 2; // 21.0 MB
  bf16_t* Sbuf  = (bf16_t*)p;  p += (size_t)2048 * 8192 * 2;     // 33.6 MB
  bf16_t* Hbuf  = (bf16_t*)p;  p += (size_t)2048 * 8192 * 2;     // 33.6 MB
  float*  cum   = (float*)p;   p += (size_t)2048 * 64 * 4;       // 0.5 MB
  float*  Dbuf  = (float*)p;   p += (size_t)2048 * 4;
  bf16_t* ybuf  = Sbuf;  // S dead after phB_k; reuse for y (bf16)
  (void)ws_size; (void)in_sizes; (void)n_in; (void)out_size;

  bf16_t* win[2]  = {win0, win1};
  bf16_t* wo[2]   = {wout0, wout1};

  // input + all weights -> bf16, one launch
  wcvt_k<<<dim3(8192, 6), 256, 0, stream>>>(
      x, abf, 8192 * 1024,
      fc1_w, wfc1, 512 * 1024,
      in_projw, win0, 2320 * 512,
      in_projw + (size_t)2320 * 512, win1, 2320 * 512,
      out_projw, wout0, 512 * 1024,
      out_projw + (size_t)512 * 1024, wout1, 512 * 1024);

  // fc1: h = gelu(x @ fc1_w^T + b)
  gemm64_bt<1><<<dim3(4, 128), 256, 0, stream>>>(abf, wfc1, h, nullptr, nullptr,
                                                 fc1_b, 512, 1024);

  for (int l = 0; l < 2; ++l) {
    ln_k<<<2048, 256, 0, stream>>>(h, ln_w + l * 512, ln_b + l * 512, abf);
    gemm64_bt<3><<<dim3(19, 128), 256, 0, stream>>>(abf, win[l], nullptr, zxbc,
                                                    dtraw, nullptr, 2320, 512);
    conv_k<<<2560, 256, 0, stream>>>(zxbc, conv_w + (size_t)l * 1280 * 4,
                                     conv_b + (size_t)l * 1280, xcbf, xcT);
    ssd1_k<<<2048, 256, 0, stream>>>(xcT, dtraw, dt_bias + l * 16,
                                     A_log + l * 16, Sbuf, cum, Dbuf);
    phB_k<<<512, 256, 0, stream>>>(Sbuf, Dbuf, Hbuf);
    ssd2_k<<<2048, 256, 0, stream>>>(xcbf, xcT, dtraw, dt_bias + l * 16, cum,
                                     Hbuf, ybuf);
    gate_k<<<2048, 256, 0, stream>>>(ybuf, xcbf, zxbc, D_p + l * 16,
                                     gnorm_w + (size_t)l * 1024, abf);
    gemm64_bt<2><<<dim3(4, 128), 256, 0, stream>>>(abf, wo[l], h, nullptr,
                                                   nullptr, nullptr, 512, 1024);
  }

  cls_k<<<2048, 256, 0, stream>>>(h, cls_w, cls_b, out);
}